// Round 4
// baseline (160.527 us; speedup 1.0000x reference)
//
#include <hip/hip_runtime.h>
#include <hip/hip_bf16.h>
#include <climits>

// Problem constants (fixed by setup_inputs): B=32, Din=1024, U=1024
#define B_DIM 32
#define DIN 1024
#define U_DIM 1024
#define FAR_FUTURE 1e6f
#define SEGS 16
#define SEG_LEN (DIN / SEGS)  // 64

// ---------------------------------------------------------------------------
// Kernel 1: stable rank sort of each batch row of tj (unchanged).
// ---------------------------------------------------------------------------
__global__ __launch_bounds__(64) void rank_sort_kernel(
    const float* __restrict__ tj, float* __restrict__ tj_sorted,
    int* __restrict__ order) {
  const int b = blockIdx.x;
  const int tile = blockIdx.y;
  __shared__ __align__(16) float v[DIN];

  const float4* src = reinterpret_cast<const float4*>(tj + b * DIN);
  float4* dst = reinterpret_cast<float4*>(v);
  for (int k = threadIdx.x; k < DIN / 4; k += 64) dst[k] = src[k];
  __syncthreads();

  const int i = tile * 64 + threadIdx.x;
  const float vi = v[i];
  int rank = 0;
#pragma unroll 8
  for (int j4 = 0; j4 < DIN / 4; ++j4) {
    float4 w = dst[j4];
    const int j = j4 * 4;
    rank += (w.x < vi) | ((w.x == vi) & (j + 0 < i));
    rank += (w.y < vi) | ((w.y == vi) & (j + 1 < i));
    rank += (w.z < vi) | ((w.z == vi) & (j + 2 < i));
    rank += (w.w < vi) | ((w.w == vi) & (j + 3 < i));
  }
  tj_sorted[b * DIN + rank] = vi;
  order[b * DIN + rank] = i;
}

// ---------------------------------------------------------------------------
// Kernel 2: segmented scan, J held in registers between passes.
// Block = 1024 threads = 16 waves; wave `seg` owns Din rows
// [seg*64, seg*64+64); lane = u within the 64-wide u-tile.
// Pass 1: load the segment's 64 J values into VGPRs while accumulating
// per-segment partials (S=ΣJ, ST=ΣJ·t). LDS exclusive scan over segments
// gives each wave its exact starting accumulators. Pass 2 replays from
// registers (no memory), evaluating S>0 && ST < tj_next*S (== ti<tj_next),
// branchlessly recording the segment's FIRST hit. Wave 0 selects the lowest
// hitting segment; fallback = position 0's (num,den), kept in wave-0 regs.
// ---------------------------------------------------------------------------
__global__ __launch_bounds__(1024, 4) void spike_scan_kernel(
    const float* __restrict__ kern, const float* __restrict__ alpha,
    const float* __restrict__ threshold, const float* __restrict__ t_min_prev,
    const float* __restrict__ t_max, const float* __restrict__ tj_sorted,
    const int* __restrict__ order, float* __restrict__ out) {
  const int b = blockIdx.y;
  const int lane = threadIdx.x & 63;
  const int seg = threadIdx.x >> 6;
  const int u = blockIdx.x * 64 + lane;

  __shared__ __align__(16) float tjs_s[DIN + 4];
  __shared__ __align__(16) int ord_s[DIN];
  __shared__ float S_part[SEGS][64];
  __shared__ float ST_part[SEGS][64];
  __shared__ int hit_s[SEGS][64];
  __shared__ float num_s[SEGS][64];
  __shared__ float den_s[SEGS][64];

  // Stage sorted times + order into LDS.
  {
    const float4* ts = reinterpret_cast<const float4*>(tj_sorted + b * DIN);
    const int4* os = reinterpret_cast<const int4*>(order + b * DIN);
    float4* tsd = reinterpret_cast<float4*>(tjs_s);
    int4* osd = reinterpret_cast<int4*>(ord_s);
    if (threadIdx.x < DIN / 4) {
      tsd[threadIdx.x] = ts[threadIdx.x];
      osd[threadIdx.x] = os[threadIdx.x];
    }
    if (threadIdx.x == 0) tjs_s[DIN] = FAR_FUTURE;
  }
  __syncthreads();

  const int i0 = seg * SEG_LEN;

  // ---- Pass 1: load J into registers, accumulate per-segment partials ----
  float Jr[SEG_LEN];
  float sS = 0.f, sST = 0.f;
#pragma unroll
  for (int k = 0; k < SEG_LEN; ++k) {
    const int i = i0 + k;
    // ord_s[i] is wave-uniform: hoist to SGPR so the load uses an SGPR base.
    const int r = __builtin_amdgcn_readfirstlane(ord_s[i]);
    const float J = kern[(size_t)r * U_DIM + u];
    Jr[k] = J;
    sS += J;
    sST = fmaf(J, tjs_s[i], sST);
  }
  S_part[seg][lane] = sS;
  ST_part[seg][lane] = sST;
  __syncthreads();

  // ---- Exclusive scan over segments (per lane/u) ----
  const float alpha_u = alpha[u];
  float S = alpha_u;                                     // J_sum + alpha folded
  float ST = fmaf(alpha_u, t_min_prev[0], threshold[u]); // numerator folded
  for (int s = 0; s < seg; ++s) {
    S += S_part[s][lane];
    ST += ST_part[s][lane];
  }

  // ---- Pass 2: replay segment from registers, find first hit ----
  bool found = false;
  float hn = 0.f, hd = 1.f;
  float fbn = 0.f, fbd = 1.f;  // global position 0 fallback (valid in seg 0)
#pragma unroll
  for (int k = 0; k < SEG_LEN; ++k) {
    const int i = i0 + k;
    const float J = Jr[k];
    S += J;
    ST = fmaf(J, tjs_s[i], ST);
    if (k == 0) { fbn = ST; fbd = S; }  // only meaningful when seg==0
    const bool cond = (S > 0.f) && (ST < tjs_s[i + 1] * S);
    const bool take = cond && !found;
    hn = take ? ST : hn;
    hd = take ? S : hd;
    found = found || cond;
  }
  hit_s[seg][lane] = found ? 1 : 0;
  num_s[seg][lane] = hn;
  den_s[seg][lane] = hd;
  __syncthreads();

  // ---- Selection (wave 0): first hitting segment wins ----
  if (seg == 0) {
    float n = fbn, d = fbd;  // fallback: position 0 (seg 0's regs)
    for (int s = 0; s < SEGS; ++s) {
      if (hit_s[s][lane]) {
        n = num_s[s][lane];
        d = den_s[s][lane];
        break;
      }
    }
    const float ti = n / d;
    const float tmax = t_max[0];
    out[b * U_DIM + u] = (ti <= tmax) ? ti : tmax;
  }
}

extern "C" void kernel_launch(void* const* d_in, const int* in_sizes, int n_in,
                              void* d_out, int out_size, void* d_ws, size_t ws_size,
                              hipStream_t stream) {
  const float* tj = (const float*)d_in[0];          // [B, DIN]
  const float* kern = (const float*)d_in[1];        // [DIN, U]
  const float* alpha = (const float*)d_in[2];       // [U]
  const float* threshold = (const float*)d_in[3];   // [U]
  const float* t_min_prev = (const float*)d_in[4];  // scalar
  const float* t_max = (const float*)d_in[5];       // scalar
  float* out = (float*)d_out;                       // [B, U]

  float* tj_sorted = (float*)d_ws;
  int* order = (int*)((char*)d_ws + (size_t)B_DIM * DIN * sizeof(float));

  rank_sort_kernel<<<dim3(B_DIM, DIN / 64), 64, 0, stream>>>(tj, tj_sorted, order);
  spike_scan_kernel<<<dim3(U_DIM / 64, B_DIM), 1024, 0, stream>>>(
      kern, alpha, threshold, t_min_prev, t_max, tj_sorted, order, out);
}

// Round 7
// 111.460 us; speedup vs baseline: 1.4402x; 1.4402x over previous
//
#include <hip/hip_runtime.h>
#include <hip/hip_bf16.h>
#include <climits>

// Problem constants (fixed by setup_inputs): B=32, Din=1024, U=1024
#define B_DIM 32
#define DIN 1024
#define U_DIM 1024
#define FAR_FUTURE 1e6f
#define SEGS 16
#define SEG_LEN (DIN / SEGS)  // 64

// ---------------------------------------------------------------------------
// Kernel 1: stable rank sort of each batch row of tj (unchanged).
// ---------------------------------------------------------------------------
__global__ __launch_bounds__(64) void rank_sort_kernel(
    const float* __restrict__ tj, float* __restrict__ tj_sorted,
    int* __restrict__ order) {
  const int b = blockIdx.x;
  const int tile = blockIdx.y;
  __shared__ __align__(16) float v[DIN];

  const float4* src = reinterpret_cast<const float4*>(tj + b * DIN);
  float4* dst = reinterpret_cast<float4*>(v);
  for (int k = threadIdx.x; k < DIN / 4; k += 64) dst[k] = src[k];
  __syncthreads();

  const int i = tile * 64 + threadIdx.x;
  const float vi = v[i];
  int rank = 0;
#pragma unroll 8
  for (int j4 = 0; j4 < DIN / 4; ++j4) {
    float4 w = dst[j4];
    const int j = j4 * 4;
    rank += (w.x < vi) | ((w.x == vi) & (j + 0 < i));
    rank += (w.y < vi) | ((w.y == vi) & (j + 1 < i));
    rank += (w.z < vi) | ((w.z == vi) & (j + 2 < i));
    rank += (w.w < vi) | ((w.w == vi) & (j + 3 < i));
  }
  tj_sorted[b * DIN + rank] = vi;
  order[b * DIN + rank] = i;
}

// ---------------------------------------------------------------------------
// Kernel 2: segmented scan, J held in registers between passes.
// NOTE: NO min-waves launch bound. R4's __launch_bounds__(1024,4) made the
// compiler cap at 64 VGPRs and spill Jr[64] to scratch (151 MB of spill
// traffic per dispatch, scan 30->68us). A 1024-thread block needs VGPR<=128
// for 1-block/CU residency; the ~110 regs this kernel wants fit there.
// ---------------------------------------------------------------------------
__global__ __launch_bounds__(1024) void spike_scan_kernel(
    const float* __restrict__ kern, const float* __restrict__ alpha,
    const float* __restrict__ threshold, const float* __restrict__ t_min_prev,
    const float* __restrict__ t_max, const float* __restrict__ tj_sorted,
    const int* __restrict__ order, float* __restrict__ out) {
  const int b = blockIdx.y;
  const int lane = threadIdx.x & 63;
  const int seg = threadIdx.x >> 6;
  const int u = blockIdx.x * 64 + lane;

  __shared__ __align__(16) float tjs_s[DIN + 4];
  __shared__ __align__(16) int ord_s[DIN];
  __shared__ float S_part[SEGS][64];
  __shared__ float ST_part[SEGS][64];
  __shared__ int hit_s[SEGS][64];
  __shared__ float num_s[SEGS][64];
  __shared__ float den_s[SEGS][64];

  // Stage sorted times + order into LDS.
  {
    const float4* ts = reinterpret_cast<const float4*>(tj_sorted + b * DIN);
    const int4* os = reinterpret_cast<const int4*>(order + b * DIN);
    float4* tsd = reinterpret_cast<float4*>(tjs_s);
    int4* osd = reinterpret_cast<int4*>(ord_s);
    if (threadIdx.x < DIN / 4) {
      tsd[threadIdx.x] = ts[threadIdx.x];
      osd[threadIdx.x] = os[threadIdx.x];
    }
    if (threadIdx.x == 0) tjs_s[DIN] = FAR_FUTURE;
  }
  __syncthreads();

  const int i0 = seg * SEG_LEN;

  // ---- Pass 1: load J into registers, accumulate per-segment partials ----
  float Jr[SEG_LEN];
  float sS = 0.f, sST = 0.f;
#pragma unroll
  for (int k = 0; k < SEG_LEN; ++k) {
    const int i = i0 + k;
    // ord_s[i] is wave-uniform: hoist to SGPR so the load uses an SGPR base.
    const int r = __builtin_amdgcn_readfirstlane(ord_s[i]);
    const float J = kern[(size_t)r * U_DIM + u];
    Jr[k] = J;
    sS += J;
    sST = fmaf(J, tjs_s[i], sST);
  }
  S_part[seg][lane] = sS;
  ST_part[seg][lane] = sST;
  __syncthreads();

  // ---- Exclusive scan over segments (per lane/u) ----
  const float alpha_u = alpha[u];
  float S = alpha_u;                                     // J_sum + alpha folded
  float ST = fmaf(alpha_u, t_min_prev[0], threshold[u]); // numerator folded
  for (int s = 0; s < seg; ++s) {
    S += S_part[s][lane];
    ST += ST_part[s][lane];
  }

  // ---- Pass 2: replay segment from registers, find first hit ----
  bool found = false;
  float hn = 0.f, hd = 1.f;
  float fbn = 0.f, fbd = 1.f;  // global position 0 fallback (valid in seg 0)
  float tjs = tjs_s[i0];       // rolling current sorted time
#pragma unroll
  for (int k = 0; k < SEG_LEN; ++k) {
    const int i = i0 + k;
    const float J = Jr[k];
    const float tjn = tjs_s[i + 1];
    S += J;
    ST = fmaf(J, tjs, ST);
    if (k == 0) { fbn = ST; fbd = S; }  // only meaningful when seg==0
    const bool cond = (S > 0.f) && (ST < tjn * S);
    const bool take = cond && !found;
    hn = take ? ST : hn;
    hd = take ? S : hd;
    found = found || cond;
    tjs = tjn;
  }
  hit_s[seg][lane] = found ? 1 : 0;
  num_s[seg][lane] = hn;
  den_s[seg][lane] = hd;
  __syncthreads();

  // ---- Selection (wave 0): first hitting segment wins ----
  if (seg == 0) {
    float n = fbn, d = fbd;  // fallback: position 0 (seg 0's regs)
    for (int s = 0; s < SEGS; ++s) {
      if (hit_s[s][lane]) {
        n = num_s[s][lane];
        d = den_s[s][lane];
        break;
      }
    }
    const float ti = n / d;
    const float tmax = t_max[0];
    out[b * U_DIM + u] = (ti <= tmax) ? ti : tmax;
  }
}

extern "C" void kernel_launch(void* const* d_in, const int* in_sizes, int n_in,
                              void* d_out, int out_size, void* d_ws, size_t ws_size,
                              hipStream_t stream) {
  const float* tj = (const float*)d_in[0];          // [B, DIN]
  const float* kern = (const float*)d_in[1];        // [DIN, U]
  const float* alpha = (const float*)d_in[2];       // [U]
  const float* threshold = (const float*)d_in[3];   // [U]
  const float* t_min_prev = (const float*)d_in[4];  // scalar
  const float* t_max = (const float*)d_in[5];       // scalar
  float* out = (float*)d_out;                       // [B, U]

  float* tj_sorted = (float*)d_ws;
  int* order = (int*)((char*)d_ws + (size_t)B_DIM * DIN * sizeof(float));

  rank_sort_kernel<<<dim3(B_DIM, DIN / 64), 64, 0, stream>>>(tj, tj_sorted, order);
  spike_scan_kernel<<<dim3(U_DIM / 64, B_DIM), 1024, 0, stream>>>(
      kern, alpha, threshold, t_min_prev, t_max, tj_sorted, order, out);
}